// Round 4
// baseline (381.067 us; speedup 1.0000x reference)
//
#include <hip/hip_runtime.h>
#include <cstdint>
#include <cstddef>

#define TT    4096          // sequence length
#define NB    4             // batch
#define DIMV  1024
#define MTOT  (NB*TT)       // 16384 rows
#define KK    1024          // GEMM K
#define NCOL  4096          // GEMM N (4*DIM)
#define NCH   64            // scan chunks
#define CL    (TT/NCH)      // 64 steps per chunk

typedef _Float16 half8 __attribute__((ext_vector_type(8)));
typedef float    f32x4 __attribute__((ext_vector_type(4)));
typedef __attribute__((address_space(1))) void GV;
typedef __attribute__((address_space(3))) void LV;

__device__ __forceinline__ void gload16(const void* g, void* l) {
    __builtin_amdgcn_global_load_lds((GV*)g, (LV*)l, 16, 0, 0);
}

// fast activations: v_exp_f32 / v_log_f32 based, overflow-safe
__device__ __forceinline__ float ftanh(float x) {          // 1 - 2/(e^2x+1)
    return 1.0f - 2.0f / (__expf(2.0f * x) + 1.0f);
}
__device__ __forceinline__ float fsig(float x) {
    return 1.0f / (1.0f + __expf(-x));
}
__device__ __forceinline__ float fsoftplus(float x) {
    return fmaxf(x, 0.0f) + __logf(1.0f + __expf(-fabsf(x)));
}

// ---------- conversions ----------
__global__ __launch_bounds__(256) void k_cvt_x(const float* __restrict__ x,
                                               _Float16* __restrict__ Xs) {
    int idx = blockIdx.x * 256 + threadIdx.x;   // [16384][1024]
    Xs[idx] = (_Float16)x[idx];
}

// W [1024][4096] fp32 -> Wt [4096][1024] fp16 (transposed, N-major for B^T GEMM)
__global__ __launch_bounds__(256) void k_cvt_w(const float* __restrict__ W,
                                               _Float16* __restrict__ Wt) {
    __shared__ float tile[32][33];
    int tx = threadIdx.x & 31, ty = threadIdx.x >> 5;   // 32 x 8
    int nb = blockIdx.x * 32, kb = blockIdx.y * 32;
#pragma unroll
    for (int j = 0; j < 32; j += 8)
        tile[ty + j][tx] = W[(size_t)(kb + ty + j) * NCOL + nb + tx];
    __syncthreads();
#pragma unroll
    for (int j = 0; j < 32; j += 8)
        Wt[(size_t)(nb + ty + j) * KK + kb + tx] = (_Float16)tile[tx][ty + j];
}

// ---------- GEMM + fused gate activations ----------
// A = Xs [16384][1024] f16, Bt = Wt [4096][1024] f16 (both row-major).
// 128x128 tile, BK=32, 4 waves (2x2), each wave 64x64 via 4x4 frags of 16x16x32.
// DOUBLE-BUFFERED (T3-minimum): issue next tile's global_load_lds BEFORE the
// current tile's ds_read+MFMA; one __syncthreads per iter (compiler emits the
// vmcnt(0)+lgkmcnt(0) drain there). LDS 2x(8+8) KB = 32 KB -> ~5 blocks/CU.
// Anti-conflict swizzle (rule 21): physical 16B slot s of row r holds logical
// slot s ^ ((r>>1)&3); linear LDS dest, pre-swizzled global src, XOR on read.
__global__ __launch_bounds__(256) void k_gemm_gates(
    const _Float16* __restrict__ Xs, const _Float16* __restrict__ Wt,
    const float* __restrict__ bias, const float* __restrict__ ibias,
    _Float16* __restrict__ gi, float* __restrict__ gf,
    _Float16* __restrict__ go, _Float16* __restrict__ gtz)
{
    __shared__ __align__(16) _Float16 Al[2][128 * 32];
    __shared__ __align__(16) _Float16 Bl[2][128 * 32];
    const int tid  = threadIdx.x;
    const int lane = tid & 63;
    const int wave = tid >> 6;
    const int m0 = blockIdx.y * 128;
    const int n0 = blockIdx.x * 128;
    const int wm = (wave >> 1) * 64;
    const int wn = (wave & 1) * 64;

    // staging: thread stages 16B at LDS offset tid*16 = (row tid>>2, phys slot tid&3),
    // plus row+64 at +4096B. Source col = swizzled logical slot.
    const int r0   = tid >> 2;                       // 0..63
    const int swz  = (tid & 3) ^ ((r0 >> 1) & 3);    // same for row r0+64
    const _Float16* aSrc = Xs + (size_t)(m0 + r0) * KK + swz * 8;
    const _Float16* bSrc = Wt + (size_t)(n0 + r0) * KK + swz * 8;

    f32x4 acc[4][4] = {};
    const int lr = lane & 15;
    const int ps = (((lane >> 4)) ^ ((lr >> 1) & 3)) * 8;   // phys slot on read

    // prologue: stage tile 0 into buf 0
    gload16(aSrc, &Al[0][tid * 8]);
    gload16(aSrc + (size_t)64 * KK, &Al[0][tid * 8 + 2048]);
    gload16(bSrc, &Bl[0][tid * 8]);
    gload16(bSrc + (size_t)64 * KK, &Bl[0][tid * 8 + 2048]);
    __syncthreads();                                 // drain vmcnt

    int cur = 0;
    for (int t = 0; t < 32; ++t) {
        if (t < 31) {                                // issue next tile's loads early
            const int kk = (t + 1) * 32;
            gload16(aSrc + kk, &Al[cur ^ 1][tid * 8]);
            gload16(aSrc + (size_t)64 * KK + kk, &Al[cur ^ 1][tid * 8 + 2048]);
            gload16(bSrc + kk, &Bl[cur ^ 1][tid * 8]);
            gload16(bSrc + (size_t)64 * KK + kk, &Bl[cur ^ 1][tid * 8 + 2048]);
        }

        half8 af[4], bfr[4];
#pragma unroll
        for (int mi = 0; mi < 4; ++mi)
            af[mi] = *(const half8*)&Al[cur][(wm + mi * 16 + lr) * 32 + ps];
#pragma unroll
        for (int nj = 0; nj < 4; ++nj)
            bfr[nj] = *(const half8*)&Bl[cur][(wn + nj * 16 + lr) * 32 + ps];
#pragma unroll
        for (int mi = 0; mi < 4; ++mi)
#pragma unroll
            for (int nj = 0; nj < 4; ++nj)
                acc[mi][nj] = __builtin_amdgcn_mfma_f32_16x16x32_f16(
                    af[mi], bfr[nj], acc[mi][nj], 0, 0, 0);

        if (t < 31) __syncthreads();                 // drain: next tile landed,
        cur ^= 1;                                    // prev reads done
    }

    // epilogue: C/D layout col=lane&15, row=(lane>>4)*4+reg  [m89-verified]
    const int gate = n0 >> 10;          // block-uniform: one gate per block
#pragma unroll
    for (int mi = 0; mi < 4; ++mi) {
        const int rowb = m0 + wm + mi * 16 + (lane >> 4) * 4;
#pragma unroll
        for (int nj = 0; nj < 4; ++nj) {
            const int col = n0 + wn + nj * 16 + lr;
            const int d   = col & 1023;
            const float bb = bias[col];
#pragma unroll
            for (int r = 0; r < 4; ++r) {
                float v = acc[mi][nj][r] + bb;
                const int idx = (rowb + r) * DIMV + d;
                if (gate == 0) {
                    gi[idx] = (_Float16)(10.0f * ftanh((v + ibias[d]) * 0.1f));
                } else if (gate == 1) {
                    gf[idx] = -fsoftplus(v);                           // log-forget
                } else if (gate == 2) {
                    go[idx] = (_Float16)fsig(v);                       // sigmoid
                } else {
                    gtz[idx] = (_Float16)ftanh(v);                     // tanh(z)
                }
            }
        }
    }
}

// ---------- chunked scan ----------
// pass1: per (channel, chunk) local scan from identity (m=-1e30): {F=sum f, M, c, n}
__global__ __launch_bounds__(256) void k_scan1(
    const _Float16* __restrict__ gi, const float* __restrict__ gf,
    const _Float16* __restrict__ gtz, float4* __restrict__ sums)
{
    const int ch = blockIdx.x * 256 + threadIdx.x;   // 0..4095
    const int chunk = blockIdx.y;
    const int b = ch >> 10, d = ch & 1023;
    int base = (b * TT + chunk * CL) * DIMV + d;
    float m = -1e30f, c = 0.0f, n = 0.0f, F = 0.0f;
#pragma unroll 4
    for (int t = 0; t < CL; ++t, base += DIMV) {
        const float iv = (float)gi[base];
        const float fv = gf[base];
        const float zv = (float)gtz[base];
        F += fv;
        const float mn = fmaxf(fv + m, iv);
        const float sc = __expf(fv + m - mn);
        const float si = __expf(iv - mn);
        c = sc * c + si * zv;
        n = sc * n + si;
        m = mn;
    }
    sums[chunk * 4096 + ch] = make_float4(F, m, c, n);
}

// pass2: sequential combine over chunks; emit incoming state per chunk
__global__ __launch_bounds__(256) void k_scan2(const float4* __restrict__ sums,
                                               float4* __restrict__ states) {
    const int ch = blockIdx.x * 256 + threadIdx.x;
    float m = -1e30f, c = 0.0f, n = 0.0f;
    for (int chunk = 0; chunk < NCH; ++chunk) {
        states[chunk * 4096 + ch] = make_float4(m, c, n, 0.0f);
        const float4 s = sums[chunk * 4096 + ch];
        const float mn = fmaxf(m + s.x, s.y);
        const float e1 = __expf(m + s.x - mn);
        const float e2 = __expf(s.y - mn);
        c = e1 * c + e2 * s.z;
        n = e1 * n + e2 * s.w;
        m = mn;
    }
}

// pass3 + RMSNorm fused: block = (batch b, chunk). 256 threads own 4 channels
// each (d0, d0+256, d0+512, d0+768) -> full 1024-row per t; block-reduce sum h^2
// per timestep (double-buffered 4-slot LDS, one barrier/step); write normalized
// fp32 out directly. h never hits memory.
__global__ __launch_bounds__(256) void k_scan3norm(
    const _Float16* __restrict__ gi, const float* __restrict__ gf,
    const _Float16* __restrict__ go, const _Float16* __restrict__ gtz,
    const float4* __restrict__ states, const float* __restrict__ scale,
    float* __restrict__ out)
{
    const int b = blockIdx.x;           // 0..3
    const int chunk = blockIdx.y;       // 0..63
    const int d0 = threadIdx.x;         // 0..255
    const int wid = threadIdx.x >> 6, lane = threadIdx.x & 63;
    __shared__ float red[2][4];

    float m[4], c[4], n[4], sv[4];
#pragma unroll
    for (int j = 0; j < 4; ++j) {
        const float4 st = states[chunk * 4096 + b * 1024 + d0 + j * 256];
        m[j] = st.x; c[j] = st.y; n[j] = st.z;
        sv[j] = scale[d0 + j * 256];
    }
    int base = (b * TT + chunk * CL) * DIMV + d0;
    for (int t = 0; t < CL; ++t, base += DIMV) {
        float h[4];
        float part = 0.0f;
#pragma unroll
        for (int j = 0; j < 4; ++j) {
            const int idx = base + j * 256;
            const float iv = (float)gi[idx];
            const float fv = gf[idx];
            const float ov = (float)go[idx];
            const float zv = (float)gtz[idx];
            const float mn = fmaxf(fv + m[j], iv);
            const float sc = __expf(fv + m[j] - mn);
            const float si = __expf(iv - mn);
            c[j] = sc * c[j] + si * zv;
            n[j] = sc * n[j] + si;
            m[j] = mn;
            h[j] = ov * c[j] / (n[j] + 1e-6f);
            part += h[j] * h[j];
        }
#pragma unroll
        for (int off = 32; off > 0; off >>= 1) part += __shfl_xor(part, off, 64);
        if (lane == 0) red[t & 1][wid] = part;
        __syncthreads();
        const float tot = red[t & 1][0] + red[t & 1][1] + red[t & 1][2] + red[t & 1][3];
        const float inv = rsqrtf(tot * (1.0f / 1024.0f) + 1e-8f);
#pragma unroll
        for (int j = 0; j < 4; ++j)
            out[base + j * 256] = h[j] * inv * sv[j];
    }
}

extern "C" void kernel_launch(void* const* d_in, const int* in_sizes, int n_in,
                              void* d_out, int out_size, void* d_ws, size_t ws_size,
                              hipStream_t stream) {
    (void)in_sizes; (void)n_in; (void)out_size; (void)ws_size;
    const float* x     = (const float*)d_in[0];
    const float* W     = (const float*)d_in[1];
    const float* bias  = (const float*)d_in[2];
    const float* ibias = (const float*)d_in[3];
    const float* scale = (const float*)d_in[4];
    float* out = (float*)d_out;

    char* ws = (char*)d_ws;
    size_t off = 0;
    _Float16* Xs = (_Float16*)(ws + off); off += (size_t)MTOT * KK * 2;     //  33.5 MB
    _Float16* Wt = (_Float16*)(ws + off); off += (size_t)NCOL * KK * 2;     //   8.4 MB
    _Float16* gi = (_Float16*)(ws + off); off += (size_t)MTOT * DIMV * 2;   //  33.5 MB
    float*    gf = (float*)(ws + off);    off += (size_t)MTOT * DIMV * 4;   //  67.1 MB
    _Float16* go = (_Float16*)(ws + off); off += (size_t)MTOT * DIMV * 2;   //  33.5 MB
    _Float16* gtz= (_Float16*)(ws + off); off += (size_t)MTOT * DIMV * 2;   //  33.5 MB
    float4* sums   = (float4*)(ws + off); off += (size_t)NCH * 4096 * 16;   //   4.2 MB
    float4* states = (float4*)(ws + off); off += (size_t)NCH * 4096 * 16;   //   4.2 MB

    k_cvt_x<<<(MTOT * DIMV) / 256, 256, 0, stream>>>(x, Xs);
    k_cvt_w<<<dim3(NCOL / 32, KK / 32), 256, 0, stream>>>(W, Wt);
    k_gemm_gates<<<dim3(NCOL / 128, MTOT / 128), 256, 0, stream>>>(
        Xs, Wt, bias, ibias, gi, gf, go, gtz);
    k_scan1<<<dim3(16, NCH), 256, 0, stream>>>(gi, gf, gtz, sums);
    k_scan2<<<16, 256, 0, stream>>>(sums, states);
    k_scan3norm<<<dim3(NB, NCH), 256, 0, stream>>>(gi, gf, go, gtz, states, scale, out);
}

// Round 6
// 356.775 us; speedup vs baseline: 1.0681x; 1.0681x over previous
//
#include <hip/hip_runtime.h>
#include <cstdint>
#include <cstddef>

#define TT    4096          // sequence length
#define NB    4             // batch
#define DIMV  1024
#define MTOT  (NB*TT)       // 16384 rows
#define KK    1024          // GEMM K
#define NCOL  4096          // GEMM N (4*DIM)
#define NCH   64            // scan chunks
#define CL    (TT/NCH)      // 64 steps per chunk

#define BM 256
#define BN 256
#define BK 32

typedef _Float16 half8 __attribute__((ext_vector_type(8)));
typedef float    f32x4 __attribute__((ext_vector_type(4)));
typedef __attribute__((address_space(1))) void GV;
typedef __attribute__((address_space(3))) void LV;

__device__ __forceinline__ void gload16(const void* g, void* l) {
    __builtin_amdgcn_global_load_lds((GV*)g, (LV*)l, 16, 0, 0);
}

// fast activations: v_exp_f32 / v_log_f32 based, overflow-safe
__device__ __forceinline__ float ftanh(float x) {          // 1 - 2/(e^2x+1)
    return 1.0f - 2.0f / (__expf(2.0f * x) + 1.0f);
}
__device__ __forceinline__ float fsig(float x) {
    return 1.0f / (1.0f + __expf(-x));
}
__device__ __forceinline__ float fsoftplus(float x) {
    return fmaxf(x, 0.0f) + __logf(1.0f + __expf(-fabsf(x)));
}

// ---------- conversions ----------
__global__ __launch_bounds__(256) void k_cvt_x(const float* __restrict__ x,
                                               _Float16* __restrict__ Xs) {
    int idx = blockIdx.x * 256 + threadIdx.x;   // [16384][1024]
    Xs[idx] = (_Float16)x[idx];
}

// W [1024][4096] fp32 -> Wt [4096][1024] fp16 (transposed, N-major for B^T GEMM)
__global__ __launch_bounds__(256) void k_cvt_w(const float* __restrict__ W,
                                               _Float16* __restrict__ Wt) {
    __shared__ float tile[32][33];
    int tx = threadIdx.x & 31, ty = threadIdx.x >> 5;   // 32 x 8
    int nb = blockIdx.x * 32, kb = blockIdx.y * 32;
#pragma unroll
    for (int j = 0; j < 32; j += 8)
        tile[ty + j][tx] = W[(size_t)(kb + ty + j) * NCOL + nb + tx];
    __syncthreads();
#pragma unroll
    for (int j = 0; j < 32; j += 8)
        Wt[(size_t)(nb + ty + j) * KK + kb + tx] = (_Float16)tile[tx][ty + j];
}

// ---------- GEMM + fused gate activations ----------
// A = Xs [16384][1024] f16, Bt = Wt [4096][1024] f16 (both row-major).
// 256x256 tile, BK=32, 8 waves (2M x 4N), wave-tile 128x64 (8x4 frags of
// 16x16x32), acc 128 VGPR. Double-buffered LDS (2 x 32KB), statically-named
// buffers (2x-unrolled K-loop), ONE barrier per K-tile. Anti-conflict
// swizzle (rule 21): phys 16B slot s of row r holds logical slot
// s ^ ((r>>1)&3); linear LDS dest, pre-swizzled global src, XOR on read.
__global__ __launch_bounds__(512) void k_gemm_gates(
    const _Float16* __restrict__ Xs, const _Float16* __restrict__ Wt,
    const float* __restrict__ bias, const float* __restrict__ ibias,
    _Float16* __restrict__ gi, float* __restrict__ gf,
    _Float16* __restrict__ go, _Float16* __restrict__ gtz)
{
    __shared__ __align__(16) _Float16 Al0[BM * BK];   // 16 KB each
    __shared__ __align__(16) _Float16 Al1[BM * BK];
    __shared__ __align__(16) _Float16 Bl0[BN * BK];
    __shared__ __align__(16) _Float16 Bl1[BN * BK];
    const int tid  = threadIdx.x;       // 0..511
    const int lane = tid & 63;
    const int wave = tid >> 6;          // 0..7

    // bijective XCD swizzle (nwg = 1024, multiple of 8): blocks sharing an
    // A-panel (consecutive ids) land on the same XCD.
    const int nwg = 16 * 64;
    int id = blockIdx.y * 16 + blockIdx.x;
    id = (id & 7) * (nwg >> 3) + (id >> 3);
    const int m0 = (id / 16) * BM;
    const int n0 = (id % 16) * BN;
    const int wm = (wave >> 2) * 128;   // 0 | 128
    const int wn = (wave & 3) * 64;     // 0,64,128,192

    // staging: thread stages rows r0 and r0+128 (16B chunks), phys slot tid&3.
    const int r0  = tid >> 2;                        // 0..127
    const int swz = (tid & 3) ^ ((r0 >> 1) & 3);     // same for r0+128
    const _Float16* aSrc = Xs + (size_t)(m0 + r0) * KK + swz * 8;
    const _Float16* bSrc = Wt + (size_t)(n0 + r0) * KK + swz * 8;

    f32x4 acc[8][4] = {};
    const int lr = lane & 15;
    const int ps = ((lane >> 4) ^ ((lr >> 1) & 3)) * 8;   // phys slot on read

#define STAGE(SRC, BUF, kkc)                                              \
    gload16(SRC + (kkc), &BUF[tid * 8]);                                  \
    gload16(SRC + (size_t)128 * KK + (kkc), &BUF[tid * 8 + 4096]);

#define COMPUTE(ABUF, BBUF)                                               \
    {                                                                     \
        half8 af[8], bf[4];                                               \
        _Pragma("unroll")                                                 \
        for (int mi = 0; mi < 8; ++mi)                                    \
            af[mi] = *(const half8*)&ABUF[(wm + mi * 16 + lr) * BK + ps]; \
        _Pragma("unroll")                                                 \
        for (int nj = 0; nj < 4; ++nj)                                    \
            bf[nj] = *(const half8*)&BBUF[(wn + nj * 16 + lr) * BK + ps]; \
        __builtin_amdgcn_s_setprio(1);                                    \
        _Pragma("unroll")                                                 \
        for (int mi = 0; mi < 8; ++mi)                                    \
            _Pragma("unroll")                                             \
            for (int nj = 0; nj < 4; ++nj)                                \
                acc[mi][nj] = __builtin_amdgcn_mfma_f32_16x16x32_f16(     \
                    af[mi], bf[nj], acc[mi][nj], 0, 0, 0);                \
        __builtin_amdgcn_s_setprio(0);                                    \
    }

    // prologue: tile 0 -> buf0
    STAGE(aSrc, Al0, 0) STAGE(bSrc, Bl0, 0)
    __syncthreads();
#pragma unroll 1
    for (int t = 0; t < 15; ++t) {
        const int k1 = (2 * t + 1) * BK, k2 = (2 * t + 2) * BK;
        STAGE(aSrc, Al1, k1) STAGE(bSrc, Bl1, k1)   // issue tile 2t+1 loads
        COMPUTE(Al0, Bl0)                           // compute tile 2t
        __syncthreads();                            // buf1 landed; buf0 reads done
        STAGE(aSrc, Al0, k2) STAGE(bSrc, Bl0, k2)   // issue tile 2t+2 loads
        COMPUTE(Al1, Bl1)                           // compute tile 2t+1
        __syncthreads();
    }
    {
        const int k1 = 31 * BK;
        STAGE(aSrc, Al1, k1) STAGE(bSrc, Bl1, k1)
        COMPUTE(Al0, Bl0)                           // tile 30
        __syncthreads();
        COMPUTE(Al1, Bl1)                           // tile 31
    }
#undef STAGE
#undef COMPUTE

    // epilogue: C/D layout col=lane&15, row=(lane>>4)*4+reg  [m89-verified]
    const int gate = n0 >> 10;          // block-uniform (256 | 1024)
#pragma unroll
    for (int mi = 0; mi < 8; ++mi) {
        const int rowb = m0 + wm + mi * 16 + (lane >> 4) * 4;
#pragma unroll
        for (int nj = 0; nj < 4; ++nj) {
            const int col = n0 + wn + nj * 16 + lr;
            const int d   = col & 1023;
            const float bb = bias[col];
#pragma unroll
            for (int r = 0; r < 4; ++r) {
                float v = acc[mi][nj][r] + bb;
                const int idx = (rowb + r) * DIMV + d;
                if (gate == 0) {
                    gi[idx] = (_Float16)(10.0f * ftanh((v + ibias[d]) * 0.1f));
                } else if (gate == 1) {
                    gf[idx] = -fsoftplus(v);                           // log-forget
                } else if (gate == 2) {
                    go[idx] = (_Float16)fsig(v);                       // sigmoid
                } else {
                    gtz[idx] = (_Float16)ftanh(v);                     // tanh(z)
                }
            }
        }
    }
}

// ---------- chunked scan ----------
// pass1: per (channel, chunk) local scan from identity (m=-1e30): {F=sum f, M, c, n}
__global__ __launch_bounds__(256) void k_scan1(
    const _Float16* __restrict__ gi, const float* __restrict__ gf,
    const _Float16* __restrict__ gtz, float4* __restrict__ sums)
{
    const int ch = blockIdx.x * 256 + threadIdx.x;   // 0..4095
    const int chunk = blockIdx.y;
    const int b = ch >> 10, d = ch & 1023;
    int base = (b * TT + chunk * CL) * DIMV + d;
    float m = -1e30f, c = 0.0f, n = 0.0f, F = 0.0f;
#pragma unroll 4
    for (int t = 0; t < CL; ++t, base += DIMV) {
        const float iv = (float)gi[base];
        const float fv = gf[base];
        const float zv = (float)gtz[base];
        F += fv;
        const float mn = fmaxf(fv + m, iv);
        const float sc = __expf(fv + m - mn);
        const float si = __expf(iv - mn);
        c = sc * c + si * zv;
        n = sc * n + si;
        m = mn;
    }
    sums[chunk * 4096 + ch] = make_float4(F, m, c, n);
}

// pass2: sequential combine over chunks; emit incoming state per chunk
__global__ __launch_bounds__(256) void k_scan2(const float4* __restrict__ sums,
                                               float4* __restrict__ states) {
    const int ch = blockIdx.x * 256 + threadIdx.x;
    float m = -1e30f, c = 0.0f, n = 0.0f;
    for (int chunk = 0; chunk < NCH; ++chunk) {
        states[chunk * 4096 + ch] = make_float4(m, c, n, 0.0f);
        const float4 s = sums[chunk * 4096 + ch];
        const float mn = fmaxf(m + s.x, s.y);
        const float e1 = __expf(m + s.x - mn);
        const float e2 = __expf(s.y - mn);
        c = e1 * c + e2 * s.z;
        n = e1 * n + e2 * s.w;
        m = mn;
    }
}

// pass3 + RMSNorm fused: block = (batch b, chunk). 256 threads own 4 channels
// each; block-reduce sum h^2 per timestep; write normalized fp32 out directly.
__global__ __launch_bounds__(256) void k_scan3norm(
    const _Float16* __restrict__ gi, const float* __restrict__ gf,
    const _Float16* __restrict__ go, const _Float16* __restrict__ gtz,
    const float4* __restrict__ states, const float* __restrict__ scale,
    float* __restrict__ out)
{
    const int b = blockIdx.x;           // 0..3
    const int chunk = blockIdx.y;       // 0..63
    const int d0 = threadIdx.x;         // 0..255
    const int wid = threadIdx.x >> 6, lane = threadIdx.x & 63;
    __shared__ float red[2][4];

    float m[4], c[4], n[4], sv[4];
#pragma unroll
    for (int j = 0; j < 4; ++j) {
        const float4 st = states[chunk * 4096 + b * 1024 + d0 + j * 256];
        m[j] = st.x; c[j] = st.y; n[j] = st.z;
        sv[j] = scale[d0 + j * 256];
    }
    int base = (b * TT + chunk * CL) * DIMV + d0;
    for (int t = 0; t < CL; ++t, base += DIMV) {
        float h[4];
        float part = 0.0f;
#pragma unroll
        for (int j = 0; j < 4; ++j) {
            const int idx = base + j * 256;
            const float iv = (float)gi[idx];
            const float fv = gf[idx];
            const float ov = (float)go[idx];
            const float zv = (float)gtz[idx];
            const float mn = fmaxf(fv + m[j], iv);
            const float sc = __expf(fv + m[j] - mn);
            const float si = __expf(iv - mn);
            c[j] = sc * c[j] + si * zv;
            n[j] = sc * n[j] + si;
            m[j] = mn;
            h[j] = ov * c[j] / (n[j] + 1e-6f);
            part += h[j] * h[j];
        }
#pragma unroll
        for (int off = 32; off > 0; off >>= 1) part += __shfl_xor(part, off, 64);
        if (lane == 0) red[t & 1][wid] = part;
        __syncthreads();
        const float tot = red[t & 1][0] + red[t & 1][1] + red[t & 1][2] + red[t & 1][3];
        const float inv = rsqrtf(tot * (1.0f / 1024.0f) + 1e-8f);
#pragma unroll
        for (int j = 0; j < 4; ++j)
            out[base + j * 256] = h[j] * inv * sv[j];
    }
}

extern "C" void kernel_launch(void* const* d_in, const int* in_sizes, int n_in,
                              void* d_out, int out_size, void* d_ws, size_t ws_size,
                              hipStream_t stream) {
    (void)in_sizes; (void)n_in; (void)out_size; (void)ws_size;
    const float* x     = (const float*)d_in[0];
    const float* W     = (const float*)d_in[1];
    const float* bias  = (const float*)d_in[2];
    const float* ibias = (const float*)d_in[3];
    const float* scale = (const float*)d_in[4];
    float* out = (float*)d_out;

    char* ws = (char*)d_ws;
    size_t off = 0;
    _Float16* Xs = (_Float16*)(ws + off); off += (size_t)MTOT * KK * 2;     //  33.5 MB
    _Float16* Wt = (_Float16*)(ws + off); off += (size_t)NCOL * KK * 2;     //   8.4 MB
    _Float16* gi = (_Float16*)(ws + off); off += (size_t)MTOT * DIMV * 2;   //  33.5 MB
    float*    gf = (float*)(ws + off);    off += (size_t)MTOT * DIMV * 4;   //  67.1 MB
    _Float16* go = (_Float16*)(ws + off); off += (size_t)MTOT * DIMV * 2;   //  33.5 MB
    _Float16* gtz= (_Float16*)(ws + off); off += (size_t)MTOT * DIMV * 2;   //  33.5 MB
    float4* sums   = (float4*)(ws + off); off += (size_t)NCH * 4096 * 16;   //   4.2 MB
    float4* states = (float4*)(ws + off); off += (size_t)NCH * 4096 * 16;   //   4.2 MB

    k_cvt_x<<<(MTOT * DIMV) / 256, 256, 0, stream>>>(x, Xs);
    k_cvt_w<<<dim3(NCOL / 32, KK / 32), 256, 0, stream>>>(W, Wt);
    k_gemm_gates<<<dim3(NCOL / BN, MTOT / BM), 512, 0, stream>>>(
        Xs, Wt, bias, ibias, gi, gf, go, gtz);
    k_scan1<<<dim3(16, NCH), 256, 0, stream>>>(gi, gf, gtz, sums);
    k_scan2<<<16, 256, 0, stream>>>(sums, states);
    k_scan3norm<<<dim3(NB, NCH), 256, 0, stream>>>(gi, gf, go, gtz, states, scale, out);
}